// Round 4
// baseline (43.563 us; speedup 1.0000x reference)
//
#include <hip/hip_runtime.h>

typedef __attribute__((ext_vector_type(8))) short short8;
typedef __attribute__((ext_vector_type(4))) float f32x4;
typedef __attribute__((ext_vector_type(4))) unsigned short u16x4;

#define DI __device__ __forceinline__

namespace {
constexpr int TOT_ = 512;                 // output row width (floats)
constexpr int XROW = 2048;                // x row width (floats) = F*D
constexpr int RPB  = 512;                 // rows per block (2 waves x 256)
constexpr int NB_  = (16384 / RPB) * 64;  // 2048 blocks
}

DI unsigned short f2bf(float v) {
    __bf16 h = (__bf16)v;                 // RNE convert
    return __builtin_bit_cast(unsigned short, h);
}

__global__ __launch_bounds__(128, 3)
void recon_kernel(const float* __restrict__ x, const float* __restrict__ W1,
                  const float* __restrict__ b1, const float* __restrict__ W2,
                  const float* __restrict__ b2, float* __restrict__ out)
{
    __shared__ __align__(16) unsigned short w1t[64 * 32];    // [n<64][k<32]
    __shared__ __align__(16) unsigned short w2t[32 * 64];    // [n<32][k<64]
    __shared__ __align__(16) unsigned short hb[2][16 * 64];  // per-wave h^T tile

    // XCD-aware remap: per XCD, all 64 features of a row-region co-resident
    // -> full 8-KB x rows read together, out lines merge in one L2.
    const int bid = blockIdx.x;                 // 0..2047
    const int xcd = bid & 7;
    const int ii  = bid >> 3;                   // 0..255
    const int f   = ii & 63;
    const int rg  = (xcd << 2) | (ii >> 6);     // 0..31 (512-row group)

    const int tid  = threadIdx.x;
    const int lane = tid & 63;
    const int wv   = tid >> 6;                  // 0..1
    const int l15  = lane & 15;
    const int kg   = lane >> 4;
    const int swz  = (l15 & 7) << 3;            // XOR swizzle (16-B granule)

    // ---- stage W1^T and W2^T into LDS as bf16 (once per block) ----
    {
        const int e0 = tid * 16;                // 128 thr x 16 = 2048 elements
        const float* W1f = W1 + f * 2048;
        const float* W2f = W2 + f * 2048;
        f32x4 v[4], u[4];
#pragma unroll
        for (int q = 0; q < 4; ++q) {
            v[q] = *(const f32x4*)(W1f + e0 + q * 4);
            u[q] = *(const f32x4*)(W2f + e0 + q * 4);
        }
#pragma unroll
        for (int j = 0; j < 16; ++j) {
            int e = e0 + j;
            w1t[(e & 63) * 32 + (e >> 6)] = f2bf(v[j >> 2][j & 3]);  // e = k*64 + n
            w2t[(e & 31) * 64 + (e >> 5)] = f2bf(u[j >> 2][j & 3]);  // e = k*32 + n
        }
    }
    __syncthreads();

    // ---- fragments (swapped-operand layout; same regs as B-fragments) ----
    short8 w1b[4];                               // W1[k][c]: c=l15, k=kg*8+j
#pragma unroll
    for (int nt = 0; nt < 4; ++nt)
        w1b[nt] = *(const short8*)&w1t[(nt * 16 + l15) * 32 + kg * 8];

    short8 w2b[2][2];                            // W2[k][c]: c=l15, k=ks*32+kg*8+j
#pragma unroll
    for (int nt = 0; nt < 2; ++nt)
#pragma unroll
        for (int ks = 0; ks < 2; ++ks)
            w2b[nt][ks] = *(const short8*)&w2t[(nt * 16 + l15) * 64 + ks * 32 + kg * 8];

    // biases along the per-lane column quad (c = nt*16 + kg*4 + j)
    f32x4 b1q[4], b2q[2];
#pragma unroll
    for (int nt = 0; nt < 4; ++nt) b1q[nt] = *(const f32x4*)(b1 + f * 64 + nt * 16 + kg * 4);
#pragma unroll
    for (int nt = 0; nt < 2; ++nt) b2q[nt] = *(const f32x4*)(b2 + f * 32 + nt * 16 + kg * 4);

    // output gather params (CARDS = [4,8,16,32]*8 ++ [1]*32)
    int card, off;
    if (f < 32) { card = 4 << (f & 3); off = (f >> 2) * 60 + card - 4; }
    else        { card = 1;            off = 480 + (f - 32); }

    unsigned short* hw = hb[wv];
    const f32x4 zero = {0.f, 0.f, 0.f, 0.f};
    const int r0 = rg * RPB + wv * 256;          // wave's 256 rows
    const float* xb = x + (size_t)(r0 + l15) * XROW + f * 32 + kg * 8;

    // prime the 4-slot rolling x buffer (row-tile 0)
    f32x4 xv[4][2];
#pragma unroll
    for (int t = 0; t < 4; ++t) {
        const float* p = xb + (size_t)(t * 16) * XROW;
        xv[t][0] = *(const f32x4*)p;
        xv[t][1] = *(const f32x4*)(p + 4);
    }

#pragma unroll
    for (int rt = 0; rt < 4; ++rt) {
#pragma unroll
        for (int t = 0; t < 4; ++t) {
            short8 af;                           // x[r=l15][k=kg*8+j]
#pragma unroll
            for (int j = 0; j < 4; ++j) {
                af[j]     = (short)f2bf(xv[t][0][j]);
                af[4 + j] = (short)f2bf(xv[t][1][j]);
            }
            if (rt < 3) {                        // rolling prefetch: refill slot t
                const float* p = xb + (size_t)((rt + 1) * 64 + t * 16) * XROW;
                xv[t][0] = *(const f32x4*)p;
                xv[t][1] = *(const f32x4*)(p + 4);
            }

            // GEMM1 swapped: lane holds h[c=nt*16+kg*4+j][r=l15]
            f32x4 c1[4];
#pragma unroll
            for (int nt = 0; nt < 4; ++nt)
                c1[nt] = __builtin_amdgcn_mfma_f32_16x16x32_bf16(w1b[nt], af, zero, 0, 0, 0);

            // bias + ReLU -> packed bf16x4 -> one ds_write_b64 per nt (swizzled)
#pragma unroll
            for (int nt = 0; nt < 4; ++nt) {
                u16x4 hv;
#pragma unroll
                for (int j = 0; j < 4; ++j) {
                    float v = c1[nt][j] + b1q[nt][j];
                    hv[j] = f2bf(v > 0.f ? v : 0.f);
                }
                *(u16x4*)&hw[(l15 * 64 + nt * 16 + kg * 4) ^ swz] = hv;
            }

            // GEMM2 A-fragments (h[r=l15][k=ks*32+kg*8+j]) from swizzled LDS
            short8 ha[2];
#pragma unroll
            for (int ks = 0; ks < 2; ++ks)
                ha[ks] = *(const short8*)&hw[(l15 * 64 + ks * 32 + kg * 8) ^ swz];

            // GEMM2 swapped: lane holds out[c=nt*16+kg*4+j][r=l15]
            f32x4 c2[2];
            c2[0] = __builtin_amdgcn_mfma_f32_16x16x32_bf16(w2b[0][0], ha[0], zero, 0, 0, 0);
            c2[0] = __builtin_amdgcn_mfma_f32_16x16x32_bf16(w2b[0][1], ha[1], c2[0], 0, 0, 0);
            if (card == 32) {
                c2[1] = __builtin_amdgcn_mfma_f32_16x16x32_bf16(w2b[1][0], ha[0], zero, 0, 0, 0);
                c2[1] = __builtin_amdgcn_mfma_f32_16x16x32_bf16(w2b[1][1], ha[1], c2[1], 0, 0, 0);
            }

            // store: each active lane writes one aligned dwordx4
            const int row = r0 + rt * 64 + t * 16 + l15;
            if (card > 1) {
                const int ntiles = (card == 32) ? 2 : 1;
                for (int nt = 0; nt < ntiles; ++nt) {
                    if (kg * 4 < card - nt * 16) {
                        f32x4 v;
#pragma unroll
                        for (int j = 0; j < 4; ++j) v[j] = c2[nt][j] + b2q[nt][j];
                        *(f32x4*)(out + (size_t)row * TOT_ + off + nt * 16 + kg * 4) = v;
                    }
                }
            } else {
                if (kg == 0)
                    out[(size_t)row * TOT_ + off] = c2[0][0] + b2q[0][0];
            }
        }
    }
}

extern "C" void kernel_launch(void* const* d_in, const int* in_sizes, int n_in,
                              void* d_out, int out_size, void* d_ws, size_t ws_size,
                              hipStream_t stream) {
    const float* x  = (const float*)d_in[0];
    const float* W1 = (const float*)d_in[1];
    const float* b1 = (const float*)d_in[2];
    const float* W2 = (const float*)d_in[3];
    const float* b2 = (const float*)d_in[4];
    float* out = (float*)d_out;
    recon_kernel<<<NB_, 128, 0, stream>>>(x, W1, b1, W2, b2, out);
}

// Round 5
// 40.185 us; speedup vs baseline: 1.0841x; 1.0841x over previous
//
#include <hip/hip_runtime.h>

typedef __attribute__((ext_vector_type(8))) short short8;
typedef __attribute__((ext_vector_type(4))) float f32x4;
typedef __attribute__((ext_vector_type(4))) unsigned short u16x4;

#define DI __device__ __forceinline__

namespace {
constexpr int TOT_ = 512;                 // output row width (floats)
constexpr int XROW = 2048;                // x row width (floats) = F*D
constexpr int BT_  = 256;                 // batch rows per block
constexpr int NB_  = (16384 / BT_) * 64;  // 4096 blocks
}

DI unsigned short f2bf(float v) {
    __bf16 h = (__bf16)v;                 // RNE convert
    return __builtin_bit_cast(unsigned short, h);
}

__global__ __launch_bounds__(256, 4)
void recon_kernel(const float* __restrict__ x, const float* __restrict__ W1,
                  const float* __restrict__ b1, const float* __restrict__ W2,
                  const float* __restrict__ b2, float* __restrict__ out)
{
    __shared__ __align__(16) unsigned short w1t[64 * 32];    // [n<64][k<32]
    __shared__ __align__(16) unsigned short w2t[32 * 64];    // [n<32][k<64]
    __shared__ __align__(16) unsigned short hb[4][16 * 64];  // per-wave h^T tile

    // XCD-aware remap: per XCD, all 64 features of one 256-row region are
    // co-resident -> full 8-KB x rows read together, out lines merge in L2.
    const int bid   = blockIdx.x;               // 0..4095
    const int f     = (bid >> 3) & 63;
    const int btile = ((bid & 7) << 3) | (bid >> 9);

    const int tid  = threadIdx.x;
    const int lane = tid & 63;
    const int wv   = tid >> 6;
    const int l15  = lane & 15;
    const int kg   = lane >> 4;
    const int swz  = (l15 & 7) << 3;            // XOR swizzle (16-B granule)
    const bool catf = (f < 32);                 // categorical (card>1) feature?

    const int b0 = btile * BT_ + wv * 64;

    // ---- issue ALL x loads first: their HBM latency hides under the
    //      weight staging + barrier that follows ----
    f32x4 xa[4][2];
#pragma unroll
    for (int t = 0; t < 4; ++t) {
        const float* xr = x + (size_t)(b0 + t * 16 + l15) * XROW + f * 32 + kg * 8;
        xa[t][0] = *(const f32x4*)xr;
        xa[t][1] = *(const f32x4*)(xr + 4);
    }

    // ---- stage W1^T (always) and W2^T (only card>1 features) as bf16 ----
    const float* W1f = W1 + f * 2048;
    const float* W2f = W2 + f * 2048;
    {
        const int e0 = tid * 8;                 // 256 thr x 8 = 2048 elements
        f32x4 v0 = *(const f32x4*)(W1f + e0);
        f32x4 v1 = *(const f32x4*)(W1f + e0 + 4);
        if (catf) {
            f32x4 u0 = *(const f32x4*)(W2f + e0);
            f32x4 u1 = *(const f32x4*)(W2f + e0 + 4);
#pragma unroll
            for (int j = 0; j < 8; ++j) {
                int e = e0 + j;
                float u = (j < 4) ? u0[j] : u1[j - 4];
                w2t[(e & 31) * 64 + (e >> 5)] = f2bf(u);   // W2: e = k*32 + n
            }
        }
#pragma unroll
        for (int j = 0; j < 8; ++j) {
            int e = e0 + j;
            float v = (j < 4) ? v0[j] : v1[j - 4];
            w1t[(e & 63) * 32 + (e >> 6)] = f2bf(v);       // W1: e = k*64 + n
        }
    }
    __syncthreads();

    // ---- fragments (swapped-operand layout) ----
    short8 w1b[4];                               // W1[k][c]: c=l15, k=kg*8+j
#pragma unroll
    for (int nt = 0; nt < 4; ++nt)
        w1b[nt] = *(const short8*)&w1t[(nt * 16 + l15) * 32 + kg * 8];

    short8 w2b[2][2] = {};                       // W2[k][c]: c=l15, k=ks*32+kg*8+j
    if (catf) {
#pragma unroll
        for (int nt = 0; nt < 2; ++nt)
#pragma unroll
            for (int ks = 0; ks < 2; ++ks)
                w2b[nt][ks] = *(const short8*)&w2t[(nt * 16 + l15) * 64 + ks * 32 + kg * 8];
    } else {
        // card==1: only output column 0 is used -> only A-row 0 of the swapped
        // GEMM2 matters. Fill every lane with W2[k][0] (rows>0 feed unused
        // outputs). 8 scalar loads, kg-dependent addresses (L2 broadcast).
#pragma unroll
        for (int ks = 0; ks < 2; ++ks)
#pragma unroll
            for (int j = 0; j < 8; ++j)
                w2b[0][ks][j] = (short)f2bf(W2f[(ks * 32 + kg * 8 + j) * 32]);
    }

    // biases along the per-lane column quad (c = nt*16 + kg*4 + j); these are
    // fed as the MFMA C-operand (accumulator init), not added in the epilogue.
    f32x4 b1q[4], b2q[2];
#pragma unroll
    for (int nt = 0; nt < 4; ++nt) b1q[nt] = *(const f32x4*)(b1 + f * 64 + nt * 16 + kg * 4);
#pragma unroll
    for (int nt = 0; nt < 2; ++nt) b2q[nt] = *(const f32x4*)(b2 + f * 32 + nt * 16 + kg * 4);

    // output gather params (CARDS = [4,8,16,32]*8 ++ [1]*32)
    int card, off;
    if (catf) { card = 4 << (f & 3); off = (f >> 2) * 60 + card - 4; }
    else      { card = 1;            off = 480 + (f - 32); }

    unsigned short* hw = hb[wv];

#pragma unroll
    for (int t = 0; t < 4; ++t) {
        short8 af;                               // x[r=l15][k=kg*8+j]
#pragma unroll
        for (int j = 0; j < 4; ++j) {
            af[j]     = (short)f2bf(xa[t][0][j]);
            af[4 + j] = (short)f2bf(xa[t][1][j]);
        }

        // GEMM1 swapped, bias in acc: lane holds h[c=nt*16+kg*4+j][r=l15]
        f32x4 c1[4];
#pragma unroll
        for (int nt = 0; nt < 4; ++nt)
            c1[nt] = __builtin_amdgcn_mfma_f32_16x16x32_bf16(w1b[nt], af, b1q[nt], 0, 0, 0);

        // ReLU -> packed bf16x4 -> one ds_write_b64 per nt (swizzled)
#pragma unroll
        for (int nt = 0; nt < 4; ++nt) {
            u16x4 hv;
#pragma unroll
            for (int j = 0; j < 4; ++j) {
                float v = c1[nt][j];
                hv[j] = f2bf(v > 0.f ? v : 0.f);
            }
            *(u16x4*)&hw[(l15 * 64 + nt * 16 + kg * 4) ^ swz] = hv;
        }

        // GEMM2 A-fragments (h[r=l15][k=ks*32+kg*8+j]) from swizzled LDS
        short8 ha[2];
#pragma unroll
        for (int ks = 0; ks < 2; ++ks)
            ha[ks] = *(const short8*)&hw[(l15 * 64 + ks * 32 + kg * 8) ^ swz];

        // GEMM2 swapped, bias in acc: lane holds out[c=nt*16+kg*4+j][r=l15]
        f32x4 c2[2];
        c2[0] = __builtin_amdgcn_mfma_f32_16x16x32_bf16(w2b[0][0], ha[0], b2q[0], 0, 0, 0);
        c2[0] = __builtin_amdgcn_mfma_f32_16x16x32_bf16(w2b[0][1], ha[1], c2[0], 0, 0, 0);
        if (card == 32) {
            c2[1] = __builtin_amdgcn_mfma_f32_16x16x32_bf16(w2b[1][0], ha[0], b2q[1], 0, 0, 0);
            c2[1] = __builtin_amdgcn_mfma_f32_16x16x32_bf16(w2b[1][1], ha[1], c2[1], 0, 0, 0);
        }

        // store: each active lane writes one aligned dwordx4 (bias already in)
        const int row = b0 + t * 16 + l15;
        if (card > 1) {
            const int ntiles = (card == 32) ? 2 : 1;
            for (int nt = 0; nt < ntiles; ++nt) {
                if (kg * 4 < card - nt * 16) {
                    f32x4 v;
#pragma unroll
                    for (int j = 0; j < 4; ++j) v[j] = c2[nt][j];
                    *(f32x4*)(out + (size_t)row * TOT_ + off + nt * 16 + kg * 4) = v;
                }
            }
        } else {
            if (kg == 0)
                out[(size_t)row * TOT_ + off] = c2[0][0];
        }
    }
}

extern "C" void kernel_launch(void* const* d_in, const int* in_sizes, int n_in,
                              void* d_out, int out_size, void* d_ws, size_t ws_size,
                              hipStream_t stream) {
    const float* x  = (const float*)d_in[0];
    const float* W1 = (const float*)d_in[1];
    const float* b1 = (const float*)d_in[2];
    const float* W2 = (const float*)d_in[3];
    const float* b2 = (const float*)d_in[4];
    float* out = (float*)d_out;
    recon_kernel<<<NB_, 256, 0, stream>>>(x, W1, b1, W2, b2, out);
}